// Round 1
// baseline (763.717 us; speedup 1.0000x reference)
//
#include <hip/hip_runtime.h>

#define LEN 4096
#define FRAME 1024
#define DCH 128
#define NFR 4

// ---------------------------------------------------------------------------
// Kernel 1: fused S-GEMM (S = Q_tq * V_tk^T, K=128) + 9-point band-sum
//           (corr(a,b) = sum_{di,dj in [-1,1]} S[a+di*32+dj, b+di*32+dj],
//            masked at image borders) + running top-4 per (a, tk) row.
// grid: 256 = n(2) * tq(4) * tk(4) * ablock(8); block: 512 threads.
// Each WG owns 128 consecutive a positions (4 image rows) of frame tq vs all
// 1024 b positions of frame tk, processed as 16 "pair-slabs" of 2 b-rows.
// ---------------------------------------------------------------------------
__global__ __launch_bounds__(512, 2) void corr_topk_kernel(
    const float* __restrict__ query,
    const float* __restrict__ value,
    int* __restrict__ idx_out)
{
    __shared__ float Ssl[192 * 64];        // S slab: 192 a' rows x 64 b' cols (2 b-rows)
    __shared__ float corrw[128 * 4 * 32];  // corr window: 128 a x 4 b-row slots x 32 wb
    __shared__ float Qc[192 * 33];         // Q K-chunk (padded)
    __shared__ float Vc[64 * 33];          // V K-chunk (padded)

    const int wg = blockIdx.x;
    const int n  = wg >> 7;
    const int tq = (wg >> 5) & 3;
    const int tk = (wg >> 3) & 3;
    const int ab = wg & 7;
    const int A0 = ab * 128;

    const float* __restrict__ Qf = query + (size_t)((n * NFR + tq) * FRAME) * DCH;
    const float* __restrict__ Vf = value + (size_t)((n * NFR + tk) * FRAME) * DCH;

    const int tid = threadIdx.x;
    const int ag = tid >> 4;   // 0..31 : GEMM a'-group (6 rows each)
    const int bg = tid & 15;   // 0..15 : GEMM b'-group (4 cols each)
    const int g  = tid >> 5;   // 0..15 : accumulate a-group (8 a each)
    const int wb = tid & 31;   // 0..31 : accumulate b-column (lane-fast)

    for (int i = tid; i < 128 * 4 * 32; i += 512) corrw[i] = 0.0f;

    // per-a top-4 state (threads 0..127; a = tid)
    float tv0 = -3.402823466e38f, tv1 = tv0, tv2 = tv0, tv3 = tv0;
    int   ti0 = 0x7fffffff, ti1 = 0x7fffffff, ti2 = 0x7fffffff, ti3 = 0x7fffffff;

#define TOPK_INSERT(vv, bb)                                                     \
    {                                                                           \
        float v_ = (vv); int b_ = (bb);                                         \
        bool c0 = (v_ > tv0) || (v_ == tv0 && b_ < ti0);                        \
        bool c1 = (v_ > tv1) || (v_ == tv1 && b_ < ti1);                        \
        bool c2 = (v_ > tv2) || (v_ == tv2 && b_ < ti2);                        \
        bool c3 = (v_ > tv3) || (v_ == tv3 && b_ < ti3);                        \
        tv3 = c3 ? (c2 ? tv2 : v_) : tv3; ti3 = c3 ? (c2 ? ti2 : b_) : ti3;     \
        tv2 = c2 ? (c1 ? tv1 : v_) : tv2; ti2 = c2 ? (c1 ? ti1 : b_) : ti2;     \
        tv1 = c1 ? (c0 ? tv0 : v_) : tv1; ti1 = c1 ? (c0 ? ti0 : b_) : ti1;     \
        tv0 = c0 ? v_ : tv0;              ti0 = c0 ? b_ : ti0;                  \
    }

    __syncthreads();

    for (int p = 0; p < 16; ++p) {
        // ---------------- S slab GEMM: rows A0-32 .. A0+159 vs b' rows [64p, 64p+64)
        float acc[6][4];
        #pragma unroll
        for (int i = 0; i < 6; ++i)
            #pragma unroll
            for (int j = 0; j < 4; ++j) acc[i][j] = 0.0f;

        for (int kc = 0; kc < 4; ++kc) {
            __syncthreads();
            // load Q chunk: 192 rows x 32 k (zero-fill out-of-frame rows)
            #pragma unroll
            for (int i = 0; i < 3; ++i) {
                int v = tid + i * 512;          // 0..1535
                int row = v >> 3;
                int kq = (v & 7) * 4;
                int agl = A0 - 32 + row;
                float4 q4 = make_float4(0.f, 0.f, 0.f, 0.f);
                if (agl >= 0 && agl < FRAME)
                    q4 = *reinterpret_cast<const float4*>(Qf + (size_t)agl * DCH + kc * 32 + kq);
                float* dst = &Qc[row * 33 + kq];
                dst[0] = q4.x; dst[1] = q4.y; dst[2] = q4.z; dst[3] = q4.w;
            }
            {   // load V chunk: 64 rows x 32 k
                int row = tid >> 3;
                int kq = (tid & 7) * 4;
                float4 v4 = *reinterpret_cast<const float4*>(Vf + (size_t)(p * 64 + row) * DCH + kc * 32 + kq);
                float* dst = &Vc[row * 33 + kq];
                dst[0] = v4.x; dst[1] = v4.y; dst[2] = v4.z; dst[3] = v4.w;
            }
            __syncthreads();

            float pacc[6][4];
            #pragma unroll
            for (int i = 0; i < 6; ++i)
                #pragma unroll
                for (int j = 0; j < 4; ++j) pacc[i][j] = 0.0f;

            #pragma unroll 8
            for (int k = 0; k < 32; ++k) {
                float qv[6], vv[4];
                #pragma unroll
                for (int i = 0; i < 6; ++i) qv[i] = Qc[(ag * 6 + i) * 33 + k];
                #pragma unroll
                for (int j = 0; j < 4; ++j) vv[j] = Vc[(bg * 4 + j) * 33 + k];
                #pragma unroll
                for (int i = 0; i < 6; ++i)
                    #pragma unroll
                    for (int j = 0; j < 4; ++j)
                        pacc[i][j] = fmaf(qv[i], vv[j], pacc[i][j]);
            }
            #pragma unroll
            for (int i = 0; i < 6; ++i)
                #pragma unroll
                for (int j = 0; j < 4; ++j) acc[i][j] += pacc[i][j];  // chunked partials: better rounding
        }
        __syncthreads();
        #pragma unroll
        for (int i = 0; i < 6; ++i)
            #pragma unroll
            for (int j = 0; j < 4; ++j)
                Ssl[(ag * 6 + i) * 64 + (bg * 4 + j)] = acc[i][j];
        __syncthreads();

        // ---------------- band-sum accumulate into corr window (rows 2p-1 .. 2p+2)
        #pragma unroll
        for (int hh = 0; hh < 4; ++hh) {
            int hb = 2 * p - 1 + hh;
            if (hb < 0 || hb >= 32) continue;
            int slot = hb & 3;
            #pragma unroll
            for (int ai = 0; ai < 8; ++ai) {
                int local = g * 8 + ai;
                int wa = local & 31;
                int ha = ab * 4 + (local >> 5);
                float sum = 0.0f;
                #pragma unroll
                for (int hp = 0; hp < 2; ++hp) {
                    const int di = hp + 1 - hh;        // compile-time per (hh,hp)
                    if (di < -1 || di > 1) continue;
                    if ((unsigned)(ha + di) >= 32u) continue;   // q-side row mask
                    #pragma unroll
                    for (int dj = -1; dj <= 1; ++dj) {
                        if ((unsigned)(wa + dj) >= 32u) continue;  // q-side col mask
                        int wbp = wb + dj;
                        if ((unsigned)wbp >= 32u) continue;        // k-side col mask
                        sum += Ssl[(local + 32 + di * 32 + dj) * 64 + hp * 32 + wbp];
                    }
                }
                corrw[local * 128 + slot * 32 + wb] += sum;
            }
        }
        __syncthreads();

        // ---------------- finalize complete rows 2p-1, 2p : top-4 update
        #pragma unroll
        for (int f = 0; f < 2; ++f) {
            int hb = 2 * p - 1 + f;
            if (hb < 0) continue;
            if (tid < 128) {
                int slot = hb & 3;
                for (int s = 0; s < 32; ++s) {
                    int w2 = (tid + s) & 31;   // staggered: bank-conflict-free
                    float v = corrw[tid * 128 + slot * 32 + w2];
                    TOPK_INSERT(v, hb * 32 + w2);
                }
            }
        }
        __syncthreads();
        // zero the two finalized slots (become rows 2p+3, 2p+4)
        for (int f = 0; f < 2; ++f) {
            int hb = 2 * p - 1 + f;
            if (hb < 0) continue;
            int slot = hb & 3;
            for (int i = tid; i < 128 * 32; i += 512)
                corrw[(i >> 5) * 128 + slot * 32 + (i & 31)] = 0.0f;
        }
        __syncthreads();
    }

    // finalize last row (31) and emit indices
    if (tid < 128) {
        const int hb = 31, slot = 3;
        for (int s = 0; s < 32; ++s) {
            int w2 = (tid + s) & 31;
            float v = corrw[tid * 128 + slot * 32 + w2];
            TOPK_INSERT(v, hb * 32 + w2);
        }
        int q = tq * FRAME + A0 + tid;
        int base = ((n * LEN + q) * NFR + tk) * 4;
        idx_out[base + 0] = ti0;
        idx_out[base + 1] = ti1;
        idx_out[base + 2] = ti2;
        idx_out[base + 3] = ti3;
    }
#undef TOPK_INSERT
}

// ---------------------------------------------------------------------------
// Kernel 2: W_out transpose (for coalesced reads in the projection).
// ---------------------------------------------------------------------------
__global__ void wt_kernel(const float* __restrict__ W, float* __restrict__ WT)
{
    int i = blockIdx.x * 256 + threadIdx.x;   // 16384
    int c = i >> 7, dd = i & 127;
    WT[c * 128 + dd] = W[dd * 128 + c];
}

// ---------------------------------------------------------------------------
// Kernel 3: sampling_locations. Flat layout of (n,q,1,t,j*4+p,2) == gid*2.
// ---------------------------------------------------------------------------
__global__ void sloc_kernel(const int* __restrict__ idxb, float* __restrict__ slout)
{
    int gid = blockIdx.x * 256 + threadIdx.x;     // < 1179648
    int pp = gid & 3;
    int t1 = gid >> 2;
    int j  = t1 % 9;
    int t2 = t1 / 9;
    int t  = t2 & 3;
    int q  = (t2 >> 2) & 4095;
    int n  = t2 >> 14;
    int sel = idxb[((n * LEN + q) * NFR + t) * 4 + pp];
    int shift = (j / 3 - 1) * 32 + (j % 3 - 1);
    int r = sel + shift;
    r = r < 0 ? 0 : (r > 961 ? 961 : r);
    float2 loc = make_float2((float)(r >> 5) * (1.0f / 32.0f),
                             (float)(r & 31) * (1.0f / 32.0f));
    *reinterpret_cast<float2*>(slout + (size_t)gid * 2) = loc;
}

// ---------------------------------------------------------------------------
// Kernel 4: gather + uniform-weight bilinear (all weights are exactly 0.25)
//           + fused output projection. One 128-thread block per (n,q).
// ---------------------------------------------------------------------------
__global__ __launch_bounds__(128) void gather_proj_kernel(
    const float* __restrict__ value, const int* __restrict__ idxb,
    const float* __restrict__ Wmat, int wt_transposed,
    const float* __restrict__ bout, float* __restrict__ outp)
{
    __shared__ float o[128];
    const int blk = blockIdx.x;
    const int n = blk >> 12;
    const int q = blk & 4095;
    const int d = threadIdx.x;

    float acc = 0.0f;
    const int* ib = idxb + (size_t)(n * LEN + q) * 16;
    for (int t = 0; t < 4; ++t) {
        const float* __restrict__ Vf = value + (size_t)((n * NFR + t) * FRAME) * DCH;
        for (int pp = 0; pp < 4; ++pp) {
            int sel = ib[t * 4 + pp];
            #pragma unroll
            for (int j = 0; j < 9; ++j) {
                const int shift = (j / 3 - 1) * 32 + (j % 3 - 1);
                int r = sel + shift;
                r = r < 0 ? 0 : (r > 961 ? 961 : r);
                int ow = r >> 5, oh = r & 31;
                #pragma unroll
                for (int dy = 0; dy < 2; ++dy)
                    #pragma unroll
                    for (int dx = 0; dx < 2; ++dx) {
                        int yi = oh - 1 + dy, xi = ow - 1 + dx;
                        // upper bounds always hold: ow<=30, oh<=31
                        if (yi >= 0 && xi >= 0)
                            acc += Vf[(size_t)(yi * 32 + xi) * DCH + d];
                    }
            }
        }
    }
    o[d] = acc * (1.0f / 576.0f);   // 0.25 bilinear * 1/(NL*P9)
    __syncthreads();
    float res = bout[d];
    if (wt_transposed) {
        #pragma unroll 8
        for (int c = 0; c < 128; ++c) res = fmaf(o[c], Wmat[c * 128 + d], res);
    } else {
        #pragma unroll 8
        for (int c = 0; c < 128; ++c) res = fmaf(o[c], Wmat[d * 128 + c], res);
    }
    outp[(size_t)(n * LEN + q) * DCH + d] = res;
}

// ---------------------------------------------------------------------------
extern "C" void kernel_launch(void* const* d_in, const int* in_sizes, int n_in,
                              void* d_out, int out_size, void* d_ws, size_t ws_size,
                              hipStream_t stream)
{
    const float* query = (const float*)d_in[0];
    // d_in[1] = reference_points (unused by the reference math)
    const float* value = (const float*)d_in[2];
    // d_in[3] = input_spatial_shapes (all 32), d_in[4] = level_start_index (unused)
    const float* W_out = (const float*)d_in[5];
    const float* b_out = (const float*)d_in[6];

    int*   idxb = (int*)d_ws;                                   // 2*4096*4*4 ints = 512 KB
    const size_t idx_bytes = (size_t)2 * LEN * NFR * 4 * sizeof(int);
    float* WT = (float*)((char*)d_ws + idx_bytes);              // 64 KB
    const bool have_wt = ws_size >= idx_bytes + 128 * 128 * sizeof(float);

    float* outp  = (float*)d_out;                               // (2,4096,128)
    float* slout = (float*)d_out + (size_t)2 * LEN * DCH;       // (2,4096,1,4,36,2)

    if (have_wt)
        hipLaunchKernelGGL(wt_kernel, dim3(64), dim3(256), 0, stream, W_out, WT);

    hipLaunchKernelGGL(corr_topk_kernel, dim3(256), dim3(512), 0, stream,
                       query, value, idxb);

    hipLaunchKernelGGL(sloc_kernel, dim3(4608), dim3(256), 0, stream, idxb, slout);

    hipLaunchKernelGGL(gather_proj_kernel, dim3(2 * LEN), dim3(128), 0, stream,
                       value, idxb,
                       have_wt ? WT : W_out, have_wt ? 1 : 0,
                       b_out, outp);
}